// Round 11
// baseline (104.674 us; speedup 1.0000x reference)
//
#include <hip/hip_runtime.h>
#include <hip/hip_bf16.h>

// Shapes fixed by reference: B=4, S=2048, D=K=2048, R=N=2048, LR=16, M=B*S=8192
#define SCALE_V 1.0f

typedef __bf16 bf16v8 __attribute__((ext_vector_type(8)));
typedef float f32v4 __attribute__((ext_vector_type(4)));

typedef const __attribute__((address_space(1))) void* gas_t;
typedef __attribute__((address_space(3))) void* las_t;
#define ASYNC_COPY16(g, l) \
    __builtin_amdgcn_global_load_lds((gas_t)(g), (las_t)(l), 16, 0, 0)
#define FENCE() asm volatile("" ::: "memory")
#define MFMA __builtin_amdgcn_mfma_f32_16x16x32_bf16

// ---------------------------------------------------------------------------
// transpose_lr: lrT[b][k][d] = bf16(lright[b][d][k])
// ---------------------------------------------------------------------------
__global__ __launch_bounds__(256) void transpose_lr_kernel(
    const float* __restrict__ lright, __bf16* __restrict__ lrT) {
    __shared__ float tile[16][273];
    const int b = blockIdx.y;
    const int d0 = blockIdx.x * 256;
    const int t = threadIdx.x;
    const float* src = lright + (size_t)b * 32768 + (size_t)d0 * 16;
    #pragma unroll
    for (int j = 0; j < 16; ++j) {
        tile[t & 15][j * 16 + (t >> 4)] = src[j * 256 + t];
    }
    __syncthreads();
    const int k = t >> 4, dcol = t & 15;
    __bf16* dst = lrT + (size_t)b * 32768 + (size_t)k * 2048 + d0;
    #pragma unroll
    for (int j = 0; j < 16; ++j) {
        dst[dcol + j * 16] = (__bf16)tile[k][dcol + j * 16];
    }
}

// ---------------------------------------------------------------------------
// prep: fused  [blocks 0..2047]  lora_t : abf = bf16(input), t = input@lora_right
//              [blocks 2048..4095] convert_w : wbf = bf16(weight)
//              [blocks 4096..4127] gram partials : G[b] = L L^T
// __launch_bounds__(256, 4): VGPR cap 128 >= ~110 live (v[64]+x[32]+lv) so the
// butterfly accumulator stays in registers (R10's VGPR_Count=68 implied a
// ~35-reg spill -> ~147 MB scratch traffic; this removes it).
// ---------------------------------------------------------------------------
__global__ __launch_bounds__(256, 4) void prep_kernel(
    const float* __restrict__ inp, const float* __restrict__ wgt,
    const __bf16* __restrict__ lrT, const float* __restrict__ lleft,
    __bf16* __restrict__ abf, __bf16* __restrict__ wbf,
    float* __restrict__ tout, float* __restrict__ gpart) {
    __shared__ float sm[256];
    const int bid = blockIdx.x;
    const int tid = threadIdx.x;

    if (bid < 2048) {
        const int row0 = bid * 4;
        const int b = row0 >> 11;
        const __bf16* lt = lrT + (size_t)b * 32768;   // [16][2048] bf16

        float x[4][8];
        #pragma unroll
        for (int rr = 0; rr < 4; ++rr) {
            const float* p = inp + (size_t)(row0 + rr) * 2048 + tid * 8;
            float4 a0 = *(const float4*)p;
            float4 a1 = *(const float4*)(p + 4);
            x[rr][0] = a0.x; x[rr][1] = a0.y; x[rr][2] = a0.z; x[rr][3] = a0.w;
            x[rr][4] = a1.x; x[rr][5] = a1.y; x[rr][6] = a1.z; x[rr][7] = a1.w;
            bf16v8 v;
            #pragma unroll
            for (int i = 0; i < 8; ++i) v[i] = (__bf16)x[rr][i];
            *(bf16v8*)(abf + (size_t)(row0 + rr) * 2048 + tid * 8) = v;
        }

        float v[64];
        #pragma unroll
        for (int k = 0; k < 16; ++k) {
            bf16v8 lb = *(const bf16v8*)(lt + (size_t)k * 2048 + tid * 8);
            float lv[8];
            #pragma unroll
            for (int i = 0; i < 8; ++i) lv[i] = (float)lb[i];
            #pragma unroll
            for (int rr = 0; rr < 4; ++rr) {
                float s = 0.f;
                #pragma unroll
                for (int i = 0; i < 8; ++i) s += x[rr][i] * lv[i];
                v[rr * 16 + k] = s;
            }
        }

        // in-register butterfly reduce-scatter (verified R4/R5)
        const int lane = tid & 63;
        const int w = tid >> 6;
        #pragma unroll
        for (int s = 1, cnt = 64; s < 64; s <<= 1, cnt >>= 1) {
            const int half = cnt >> 1;
            const bool up = (lane & s) != 0;
            #pragma unroll
            for (int i = 0; i < 32; ++i) {
                if (i < half) {
                    float keep = up ? v[i + half] : v[i];
                    float give = up ? v[i] : v[i + half];
                    v[i] = keep + __shfl_xor(give, s, 64);
                }
            }
        }
        const int rev = ((lane & 1) << 5) | ((lane & 2) << 3) | ((lane & 4) << 1) |
                        ((lane & 8) >> 1) | ((lane & 16) >> 3) | ((lane & 32) >> 5);
        sm[w * 64 + rev] = v[0];
        __syncthreads();
        if (tid < 64) {
            tout[(size_t)row0 * 16 + tid] =
                sm[tid] + sm[64 + tid] + sm[128 + tid] + sm[192 + tid];
        }
    } else if (bid < 4096) {
        const int i = ((bid - 2048) * 256 + tid) * 8;
        float4 x0 = *(const float4*)(wgt + i);
        float4 x1 = *(const float4*)(wgt + i + 4);
        bf16v8 v;
        v[0] = (__bf16)x0.x; v[1] = (__bf16)x0.y; v[2] = (__bf16)x0.z; v[3] = (__bf16)x0.w;
        v[4] = (__bf16)x1.x; v[5] = (__bf16)x1.y; v[6] = (__bf16)x1.z; v[7] = (__bf16)x1.w;
        *(bf16v8*)(wbf + i) = v;
    } else {
        const int g = bid - 4096;
        const int b = g >> 3, c = g & 7;
        const int k = tid >> 4, j = tid & 15;
        const float* pk = lleft + ((size_t)b * 16 + k) * 2048 + c * 256;
        const float* pj = lleft + ((size_t)b * 16 + j) * 2048 + c * 256;
        float s = 0.f;
        #pragma unroll 4
        for (int r = 0; r < 256; r += 4) {
            float4 a = *(const float4*)(pk + r);
            float4 d = *(const float4*)(pj + r);
            s += a.x * d.x + a.y * d.y + a.z * d.z + a.w * d.w;
        }
        gpart[((size_t)b * 8 + c) * 256 + tid] = s;
    }
}

// ---------------------------------------------------------------------------
// gemm (R11 = R10, frozen): 256x256, BK=64, 8 waves, 4 phases/K-tile x 2 dbuf,
// chunked XCD swizzle, XOR LDS swizzle, setprio, one vmcnt(6)/K-tile,
// unroll-2, norm fused into epilogue.
// ---------------------------------------------------------------------------
__global__ __launch_bounds__(512, 2) void gemm_ep_kernel(
    const __bf16* __restrict__ abf, const __bf16* __restrict__ wbf,
    const float* __restrict__ bias, const float* __restrict__ traw,
    const float* __restrict__ gpart, const float* __restrict__ lleft,
    float* __restrict__ out) {
    __shared__ __attribute__((aligned(16))) char smem[131072];  // As[2][256][64] | Bs[2][256][64] bf16

    const int tid  = threadIdx.x;
    const int w    = tid >> 6;           // wave 0..7
    const int lane = tid & 63;
    const int l3   = lane >> 3, l7 = lane & 7;
    const int wm   = w >> 2;             // 0..1 (M half)
    const int wn   = w & 3;              // 0..3 (N quarter)
    const int fr   = lane & 15;

    // chunked XCD swizzle: xcd = bid&7 owns tile_m in [4*xcd, 4*xcd+4), all tile_n
    const int xcd   = blockIdx.x & 7;
    const int local = blockIdx.x >> 3;          // 0..31
    const int tile_n = local & 7;
    const int tile_m = (xcd << 2) | (local >> 3);
    const int row0 = tile_m * 256;
    const int col0 = tile_n * 256;

    // staging: pre-swizzled global source column
    const int cswz = ((l7 ^ l3) * 8);                       // elements
    const size_t aG0 = (size_t)(row0 + 8 * w + l3) * 2048 + cswz;
    const int bCh = 64 * (w >> 2) + 8 * (w & 3);
    const size_t bG0 = (size_t)(col0 + bCh + l3) * 2048 + cswz;
    char* const aDst = smem + 8 * w * 128 + lane * 16;
    char* const bDst = smem + 65536 + bCh * 128 + lane * 16;

#define STAGE_A(BUFOFF, S, KKEL)                                                         \
    do {                                                                                 \
        ASYNC_COPY16(abf + aG0 + (size_t)((S)*64) * 2048 + (KKEL),  aDst + (BUFOFF) + (S)*8192);          \
        ASYNC_COPY16(abf + aG0 + (size_t)((S)*64 + 128) * 2048 + (KKEL), aDst + (BUFOFF) + (S)*8192 + 16384); \
    } while (0)
#define STAGE_B(BUFOFF, S, KKEL)                                                         \
    do {                                                                                 \
        ASYNC_COPY16(wbf + bG0 + (size_t)((S)*32) * 2048 + (KKEL),  bDst + (BUFOFF) + (S)*4096);          \
        ASYNC_COPY16(wbf + bG0 + (size_t)((S)*32 + 128) * 2048 + (KKEL), bDst + (BUFOFF) + (S)*4096 + 16384); \
    } while (0)

    // fragment read bases (byte addrs), swizzled k-offset per lane
    const int kx0 = (((lane >> 4) * 16) ^ (l7 << 4));
    const int kx1 = ((64 + (lane >> 4) * 16) ^ (l7 << 4));
    const char* const aRd = smem + (wm * 128 + fr) * 128;
    const char* const bRd = smem + 65536 + (wn * 64 + fr) * 128;

    f32v4 acc[8][4];
    #pragma unroll
    for (int m = 0; m < 8; ++m)
        #pragma unroll
        for (int n = 0; n < 4; ++n) {
            acc[m][n][0] = 0.f; acc[m][n][1] = 0.f;
            acc[m][n][2] = 0.f; acc[m][n][3] = 0.f;
        }

    // ---- prologue: stage kt0 fully + kt1 {B-lo, B-hi, A-lo} ----
    STAGE_A(0, 0, 0);      // A-Mlo(0)
    STAGE_B(0, 0, 0);      // B-Nlo(0)
    STAGE_B(0, 1, 0);      // B-Nhi(0)
    STAGE_A(0, 1, 0);      // A-Mhi(0)
    STAGE_B(32768, 0, 64); // B-Nlo(1)
    STAGE_B(32768, 1, 64); // B-Nhi(1)
    STAGE_A(32768, 0, 64); // A-Mlo(1)
    asm volatile("s_waitcnt vmcnt(6)" ::: "memory");  // kt0's 8 loads complete
    FENCE(); __builtin_amdgcn_s_barrier(); FENCE();

    #pragma unroll 2
    for (int kt = 0; kt < 32; ++kt) {
        const int bo = (kt & 1) * 32768;
        const int bn = bo ^ 32768;
        const size_t kk1 = (size_t)((kt + 1) & 31) * 64;
        const size_t kk2 = (size_t)((kt + 2) & 31) * 64;
        bf16v8 af[4][2], bl[2][2], bh[2][2];

        // ===== phase 1: read A-Mlo + B-Nlo; stage A-Mhi(kt+1); MFMA m0-3 x n0-1 =====
        #pragma unroll
        for (int m = 0; m < 4; ++m) {
            af[m][0] = *(const bf16v8*)(aRd + bo + m * 2048 + kx0);
            af[m][1] = *(const bf16v8*)(aRd + bo + m * 2048 + kx1);
        }
        #pragma unroll
        for (int n = 0; n < 2; ++n) {
            bl[n][0] = *(const bf16v8*)(bRd + bo + n * 2048 + kx0);
            bl[n][1] = *(const bf16v8*)(bRd + bo + n * 2048 + kx1);
        }
        STAGE_A(bn, 1, kk1);
        FENCE(); __builtin_amdgcn_s_barrier(); FENCE();
        __builtin_amdgcn_s_setprio(1);
        #pragma unroll
        for (int m = 0; m < 4; ++m)
            #pragma unroll
            for (int n = 0; n < 2; ++n) {
                acc[m][n] = MFMA(af[m][0], bl[n][0], acc[m][n], 0, 0, 0);
                acc[m][n] = MFMA(af[m][1], bl[n][1], acc[m][n], 0, 0, 0);
            }
        __builtin_amdgcn_s_setprio(0);
        FENCE(); __builtin_amdgcn_s_barrier(); FENCE();

        // ===== phase 2: read B-Nhi; stage B-Nlo(kt+2); MFMA m0-3 x n2-3 =====
        #pragma unroll
        for (int n = 0; n < 2; ++n) {
            bh[n][0] = *(const bf16v8*)(bRd + bo + (n + 2) * 2048 + kx0);
            bh[n][1] = *(const bf16v8*)(bRd + bo + (n + 2) * 2048 + kx1);
        }
        STAGE_B(bo, 0, kk2);
        FENCE(); __builtin_amdgcn_s_barrier(); FENCE();
        __builtin_amdgcn_s_setprio(1);
        #pragma unroll
        for (int m = 0; m < 4; ++m)
            #pragma unroll
            for (int n = 0; n < 2; ++n) {
                acc[m][n + 2] = MFMA(af[m][0], bh[n][0], acc[m][n + 2], 0, 0, 0);
                acc[m][n + 2] = MFMA(af[m][1], bh[n][1], acc[m][n + 2], 0, 0, 0);
            }
        __builtin_amdgcn_s_setprio(0);
        FENCE(); __builtin_amdgcn_s_barrier(); FENCE();

        // ===== phase 3: read A-Mhi; stage B-Nhi(kt+2); MFMA m4-7 x n2-3 =====
        #pragma unroll
        for (int m = 0; m < 4; ++m) {
            af[m][0] = *(const bf16v8*)(aRd + bo + (m + 4) * 2048 + kx0);
            af[m][1] = *(const bf16v8*)(aRd + bo + (m + 4) * 2048 + kx1);
        }
        STAGE_B(bo, 1, kk2);
        FENCE(); __builtin_amdgcn_s_barrier(); FENCE();
        __builtin_amdgcn_s_setprio(1);
        #pragma unroll
        for (int m = 0; m < 4; ++m)
            #pragma unroll
            for (int n = 0; n < 2; ++n) {
                acc[m + 4][n + 2] = MFMA(af[m][0], bh[n][0], acc[m + 4][n + 2], 0, 0, 0);
                acc[m + 4][n + 2] = MFMA(af[m][1], bh[n][1], acc[m + 4][n + 2], 0, 0, 0);
            }
        __builtin_amdgcn_s_setprio(0);
        FENCE(); __builtin_amdgcn_s_barrier(); FENCE();

        // ===== phase 4: stage A-Mlo(kt+2); vmcnt(6); MFMA m4-7 x n0-1 =====
        STAGE_A(bo, 0, kk2);
        asm volatile("s_waitcnt vmcnt(6)" ::: "memory");
        FENCE(); __builtin_amdgcn_s_barrier(); FENCE();
        __builtin_amdgcn_s_setprio(1);
        #pragma unroll
        for (int m = 0; m < 4; ++m)
            #pragma unroll
            for (int n = 0; n < 2; ++n) {
                acc[m + 4][n] = MFMA(af[m][0], bl[n][0], acc[m + 4][n], 0, 0, 0);
                acc[m + 4][n] = MFMA(af[m][1], bl[n][1], acc[m + 4][n], 0, 0, 0);
            }
        __builtin_amdgcn_s_setprio(0);
        FENCE(); __builtin_amdgcn_s_barrier(); FENCE();
    }

    // ---- fused norm + LoRA extension ----
    asm volatile("s_waitcnt vmcnt(0)" ::: "memory");
    __syncthreads();
    {
        bf16v8 zv;
        #pragma unroll
        for (int i = 0; i < 8; ++i) zv[i] = (__bf16)0.f;

        __bf16* tE  = (__bf16*)smem;           // [256][40] bf16 (pad 8)
        __bf16* LE  = (__bf16*)(smem + 20480); // [256][40]
        float*  gsf = (float*)(smem + 40960);  // G[16][16]
        const int bb = row0 >> 11;

        if (tid < 256) {
            float g = 0.f;
            #pragma unroll
            for (int c = 0; c < 8; ++c) g += gpart[((size_t)bb * 8 + c) * 256 + tid];
            gsf[tid] = g;
        }
        {
            const int r = tid >> 1;
            const int h = (tid & 1) * 8;
            const float* lp = lleft + ((size_t)bb * 16 + h) * 2048 + col0 + r;
            bf16v8 lv;
            #pragma unroll
            for (int i = 0; i < 8; ++i) lv[i] = (__bf16)lp[(size_t)i * 2048];
            *(bf16v8*)(LE + r * 40 + h) = lv;
            *(bf16v8*)(LE + r * 40 + 16 + h) = zv;
        }
        __syncthreads();
        if (tid < 256) {
            const float* tp = traw + (size_t)(row0 + tid) * 16;
            float4 a0 = *(const float4*)(tp);
            float4 a1 = *(const float4*)(tp + 4);
            float4 a2 = *(const float4*)(tp + 8);
            float4 a3 = *(const float4*)(tp + 12);
            float tv[16] = {a0.x, a0.y, a0.z, a0.w, a1.x, a1.y, a1.z, a1.w,
                            a2.x, a2.y, a2.z, a2.w, a3.x, a3.y, a3.z, a3.w};
            float q = 0.f;
            #pragma unroll
            for (int k = 0; k < 16; ++k) {
                float s = 0.f;
                #pragma unroll
                for (int j = 0; j < 16; ++j) s += gsf[k * 16 + j] * tv[j];
                q += tv[k] * s;
            }
            const float sc = SCALE_V * rsqrtf(q);
            bf16v8 t0v, t1v;
            #pragma unroll
            for (int i = 0; i < 8; ++i) {
                t0v[i] = (__bf16)(tv[i] * sc);
                t1v[i] = (__bf16)(tv[8 + i] * sc);
            }
            *(bf16v8*)(tE + tid * 40)      = t0v;
            *(bf16v8*)(tE + tid * 40 + 8)  = t1v;
            *(bf16v8*)(tE + tid * 40 + 16) = zv;
            *(bf16v8*)(tE + tid * 40 + 24) = zv;
        }
        __syncthreads();
    }
    {
        const __bf16* tE = (const __bf16*)smem;
        const __bf16* LE = (const __bf16*)(smem + 20480);
        const int ko = (lane >> 4) * 8;
        bf16v8 bE[4];
        #pragma unroll
        for (int n = 0; n < 4; ++n)
            bE[n] = *(const bf16v8*)(LE + (wn * 64 + n * 16 + fr) * 40 + ko);
        #pragma unroll
        for (int m = 0; m < 8; ++m) {
            bf16v8 aE = *(const bf16v8*)(tE + (wm * 128 + m * 16 + fr) * 40 + ko);
            #pragma unroll
            for (int n = 0; n < 4; ++n)
                acc[m][n] = MFMA(aE, bE[n], acc[m][n], 0, 0, 0);
        }
    }

    // ---- writeout + bias ----
    #pragma unroll
    for (int n = 0; n < 4; ++n) {
        const int gc = col0 + wn * 64 + n * 16 + fr;
        const float bv = bias[gc];
        #pragma unroll
        for (int m = 0; m < 8; ++m) {
            #pragma unroll
            for (int j = 0; j < 4; ++j) {
                const int gr = row0 + wm * 128 + m * 16 + (lane >> 4) * 4 + j;
                out[(size_t)gr * 2048 + gc] = acc[m][n][j] + bv;
            }
        }
    }
#undef STAGE_A
#undef STAGE_B
}

// ---------------------------------------------------------------------------
extern "C" void kernel_launch(void* const* d_in, const int* in_sizes, int n_in,
                              void* d_out, int out_size, void* d_ws, size_t ws_size,
                              hipStream_t stream) {
    const float* inp  = (const float*)d_in[0];   // [4,2048,2048]
    const float* wgt  = (const float*)d_in[1];   // [2048,2048]
    const float* bias = (const float*)d_in[2];   // [2048]
    const float* lrt  = (const float*)d_in[3];   // [4,2048,16]
    const float* llf  = (const float*)d_in[4];   // [4,16,2048]
    float* out = (float*)d_out;                  // [4,2048,2048]

    char* ws = (char*)d_ws;
    __bf16* abf  = (__bf16*)ws;                    // 33,554,432 B
    __bf16* wbf  = (__bf16*)(ws + 33554432);       //  8,388,608 B
    float*  tbuf = (float*)(ws + 41943040);        //    524,288 B (raw t)
    float*  gprt = (float*)(ws + 42467328);        //     32,768 B
    __bf16* lrT  = (__bf16*)(ws + 42500096);       //    262,144 B (bf16)

    transpose_lr_kernel<<<dim3(8, 4), 256, 0, stream>>>(lrt, lrT);
    prep_kernel<<<4128, 256, 0, stream>>>(inp, wgt, lrT, llf, abf, wbf, tbuf, gprt);
    gemm_ep_kernel<<<dim3(256), 512, 0, stream>>>(abf, wbf, bias, tbuf, gprt, llf, out);
}

// Round 12
// 103.492 us; speedup vs baseline: 1.0114x; 1.0114x over previous
//
#include <hip/hip_runtime.h>
#include <hip/hip_bf16.h>

// Shapes fixed by reference: B=4, S=2048, D=K=2048, R=N=2048, LR=16, M=B*S=8192
#define SCALE_V 1.0f

typedef __bf16 bf16v8 __attribute__((ext_vector_type(8)));
typedef float f32v4 __attribute__((ext_vector_type(4)));

typedef const __attribute__((address_space(1))) void* gas_t;
typedef __attribute__((address_space(3))) void* las_t;
#define ASYNC_COPY16(g, l) \
    __builtin_amdgcn_global_load_lds((gas_t)(g), (las_t)(l), 16, 0, 0)
#define FENCE() asm volatile("" ::: "memory")
#define MFMA __builtin_amdgcn_mfma_f32_16x16x32_bf16

// ---------------------------------------------------------------------------
// transpose_lr: lrT[b][k][d] = bf16(lright[b][d][k])
// ---------------------------------------------------------------------------
__global__ __launch_bounds__(256) void transpose_lr_kernel(
    const float* __restrict__ lright, __bf16* __restrict__ lrT) {
    __shared__ float tile[16][273];
    const int b = blockIdx.y;
    const int d0 = blockIdx.x * 256;
    const int t = threadIdx.x;
    const float* src = lright + (size_t)b * 32768 + (size_t)d0 * 16;
    #pragma unroll
    for (int j = 0; j < 16; ++j) {
        tile[t & 15][j * 16 + (t >> 4)] = src[j * 256 + t];
    }
    __syncthreads();
    const int k = t >> 4, dcol = t & 15;
    __bf16* dst = lrT + (size_t)b * 32768 + (size_t)k * 2048 + d0;
    #pragma unroll
    for (int j = 0; j < 16; ++j) {
        dst[dcol + j * 16] = (__bf16)tile[k][dcol + j * 16];
    }
}

// ---------------------------------------------------------------------------
// prep: fused  [blocks 0..2047]  lora_t : abf = bf16(input), t = input@lora_right
//              [blocks 2048..4095] convert_w : wbf = bf16(weight)
//              [blocks 4096..4127] gram partials : G[b] = L L^T
// ---------------------------------------------------------------------------
__global__ __launch_bounds__(256, 4) void prep_kernel(
    const float* __restrict__ inp, const float* __restrict__ wgt,
    const __bf16* __restrict__ lrT, const float* __restrict__ lleft,
    __bf16* __restrict__ abf, __bf16* __restrict__ wbf,
    float* __restrict__ tout, float* __restrict__ gpart) {
    __shared__ float sm[256];
    const int bid = blockIdx.x;
    const int tid = threadIdx.x;

    if (bid < 2048) {
        const int row0 = bid * 4;
        const int b = row0 >> 11;
        const __bf16* lt = lrT + (size_t)b * 32768;   // [16][2048] bf16

        float x[4][8];
        #pragma unroll
        for (int rr = 0; rr < 4; ++rr) {
            const float* p = inp + (size_t)(row0 + rr) * 2048 + tid * 8;
            float4 a0 = *(const float4*)p;
            float4 a1 = *(const float4*)(p + 4);
            x[rr][0] = a0.x; x[rr][1] = a0.y; x[rr][2] = a0.z; x[rr][3] = a0.w;
            x[rr][4] = a1.x; x[rr][5] = a1.y; x[rr][6] = a1.z; x[rr][7] = a1.w;
            bf16v8 v;
            #pragma unroll
            for (int i = 0; i < 8; ++i) v[i] = (__bf16)x[rr][i];
            *(bf16v8*)(abf + (size_t)(row0 + rr) * 2048 + tid * 8) = v;
        }

        float v[64];
        #pragma unroll
        for (int k = 0; k < 16; ++k) {
            bf16v8 lb = *(const bf16v8*)(lt + (size_t)k * 2048 + tid * 8);
            float lv[8];
            #pragma unroll
            for (int i = 0; i < 8; ++i) lv[i] = (float)lb[i];
            #pragma unroll
            for (int rr = 0; rr < 4; ++rr) {
                float s = 0.f;
                #pragma unroll
                for (int i = 0; i < 8; ++i) s += x[rr][i] * lv[i];
                v[rr * 16 + k] = s;
            }
        }

        // in-register butterfly reduce-scatter (verified R4/R5)
        const int lane = tid & 63;
        const int w = tid >> 6;
        #pragma unroll
        for (int s = 1, cnt = 64; s < 64; s <<= 1, cnt >>= 1) {
            const int half = cnt >> 1;
            const bool up = (lane & s) != 0;
            #pragma unroll
            for (int i = 0; i < 32; ++i) {
                if (i < half) {
                    float keep = up ? v[i + half] : v[i];
                    float give = up ? v[i] : v[i + half];
                    v[i] = keep + __shfl_xor(give, s, 64);
                }
            }
        }
        const int rev = ((lane & 1) << 5) | ((lane & 2) << 3) | ((lane & 4) << 1) |
                        ((lane & 8) >> 1) | ((lane & 16) >> 3) | ((lane & 32) >> 5);
        sm[w * 64 + rev] = v[0];
        __syncthreads();
        if (tid < 64) {
            tout[(size_t)row0 * 16 + tid] =
                sm[tid] + sm[64 + tid] + sm[128 + tid] + sm[192 + tid];
        }
    } else if (bid < 4096) {
        const int i = ((bid - 2048) * 256 + tid) * 8;
        float4 x0 = *(const float4*)(wgt + i);
        float4 x1 = *(const float4*)(wgt + i + 4);
        bf16v8 v;
        v[0] = (__bf16)x0.x; v[1] = (__bf16)x0.y; v[2] = (__bf16)x0.z; v[3] = (__bf16)x0.w;
        v[4] = (__bf16)x1.x; v[5] = (__bf16)x1.y; v[6] = (__bf16)x1.z; v[7] = (__bf16)x1.w;
        *(bf16v8*)(wbf + i) = v;
    } else {
        const int g = bid - 4096;
        const int b = g >> 3, c = g & 7;
        const int k = tid >> 4, j = tid & 15;
        const float* pk = lleft + ((size_t)b * 16 + k) * 2048 + c * 256;
        const float* pj = lleft + ((size_t)b * 16 + j) * 2048 + c * 256;
        float s = 0.f;
        #pragma unroll 4
        for (int r = 0; r < 256; r += 4) {
            float4 a = *(const float4*)(pk + r);
            float4 d = *(const float4*)(pj + r);
            s += a.x * d.x + a.y * d.y + a.z * d.z + a.w * d.w;
        }
        gpart[((size_t)b * 8 + c) * 256 + tid] = s;
    }
}

// ---------------------------------------------------------------------------
// gemm (R12): register-pipelined 4-phase, ONE barrier/phase (4/K-tile).
// Phase p's MFMA consumes fragments read in an EARLIER phase (only p1 blocks
// on lgkm), overlapping the LDS-read pipe (~1900 cyc/K-tile) with the MFMA
// pipe (~2483 cyc/K-tile) instead of serializing them (R11: ~4390 measured).
// Stage issue order IDENTICAL to R8 (Ahi@p1, Blo@p2, Bhi@p3, Alo@p4 + one
// vmcnt(6)@p4) -> after p4(kt) barrier, ALL kt+1 data complete.
// Overwrite-after-read: Alo/Blo/Bhi(bo) last read p1(kt), overwritten
// p4/p2/p3(kt); Ahi(bo) read p2(kt), overwritten p1(kt+1) -- >=1 barrier
// between each. Epilogue: fused norm + LoRA K=32 extension (unchanged).
// ---------------------------------------------------------------------------
__global__ __launch_bounds__(512, 2) void gemm_ep_kernel(
    const __bf16* __restrict__ abf, const __bf16* __restrict__ wbf,
    const float* __restrict__ bias, const float* __restrict__ traw,
    const float* __restrict__ gpart, const float* __restrict__ lleft,
    float* __restrict__ out) {
    __shared__ __attribute__((aligned(16))) char smem[131072];  // As[2][256][64] | Bs[2][256][64] bf16

    const int tid  = threadIdx.x;
    const int w    = tid >> 6;           // wave 0..7
    const int lane = tid & 63;
    const int l3   = lane >> 3, l7 = lane & 7;
    const int wm   = w >> 2;             // 0..1 (M half)
    const int wn   = w & 3;              // 0..3 (N quarter)
    const int fr   = lane & 15;

    // chunked XCD swizzle: xcd = bid&7 owns tile_m in [4*xcd, 4*xcd+4), all tile_n
    const int xcd   = blockIdx.x & 7;
    const int local = blockIdx.x >> 3;          // 0..31
    const int tile_n = local & 7;
    const int tile_m = (xcd << 2) | (local >> 3);
    const int row0 = tile_m * 256;
    const int col0 = tile_n * 256;

    // staging: pre-swizzled global source column
    const int cswz = ((l7 ^ l3) * 8);                       // elements
    const size_t aG0 = (size_t)(row0 + 8 * w + l3) * 2048 + cswz;
    const int bCh = 64 * (w >> 2) + 8 * (w & 3);
    const size_t bG0 = (size_t)(col0 + bCh + l3) * 2048 + cswz;
    char* const aDst = smem + 8 * w * 128 + lane * 16;
    char* const bDst = smem + 65536 + bCh * 128 + lane * 16;

#define STAGE_A(BUFOFF, S, KKEL)                                                         \
    do {                                                                                 \
        ASYNC_COPY16(abf + aG0 + (size_t)((S)*64) * 2048 + (KKEL),  aDst + (BUFOFF) + (S)*8192);          \
        ASYNC_COPY16(abf + aG0 + (size_t)((S)*64 + 128) * 2048 + (KKEL), aDst + (BUFOFF) + (S)*8192 + 16384); \
    } while (0)
#define STAGE_B(BUFOFF, S, KKEL)                                                         \
    do {                                                                                 \
        ASYNC_COPY16(wbf + bG0 + (size_t)((S)*32) * 2048 + (KKEL),  bDst + (BUFOFF) + (S)*4096);          \
        ASYNC_COPY16(wbf + bG0 + (size_t)((S)*32 + 128) * 2048 + (KKEL), bDst + (BUFOFF) + (S)*4096 + 16384); \
    } while (0)

    // fragment read bases (byte addrs), swizzled k-offset per lane
    const int kx0 = (((lane >> 4) * 16) ^ (l7 << 4));
    const int kx1 = ((64 + (lane >> 4) * 16) ^ (l7 << 4));
    const char* const aRd = smem + (wm * 128 + fr) * 128;
    const char* const bRd = smem + 65536 + (wn * 64 + fr) * 128;

    f32v4 acc[8][4];
    #pragma unroll
    for (int m = 0; m < 8; ++m)
        #pragma unroll
        for (int n = 0; n < 4; ++n) {
            acc[m][n][0] = 0.f; acc[m][n][1] = 0.f;
            acc[m][n][2] = 0.f; acc[m][n][3] = 0.f;
        }

    // ---- prologue: stage kt0 fully + kt1 {B-lo, B-hi, A-lo} ----
    STAGE_A(0, 0, 0);      // A-Mlo(0)
    STAGE_B(0, 0, 0);      // B-Nlo(0)
    STAGE_B(0, 1, 0);      // B-Nhi(0)
    STAGE_A(0, 1, 0);      // A-Mhi(0)
    STAGE_B(32768, 0, 64); // B-Nlo(1)
    STAGE_B(32768, 1, 64); // B-Nhi(1)
    STAGE_A(32768, 0, 64); // A-Mlo(1)
    asm volatile("s_waitcnt vmcnt(6)" ::: "memory");  // kt0's 8 loads complete
    FENCE(); __builtin_amdgcn_s_barrier(); FENCE();

    #pragma unroll 2
    for (int kt = 0; kt < 32; ++kt) {
        const int bo = (kt & 1) * 32768;
        const int bn = bo ^ 32768;
        const size_t kk1 = (size_t)((kt + 1) & 31) * 64;
        const size_t kk2 = (size_t)((kt + 2) & 31) * 64;
        bf16v8 afA[4][2], afB[4][2], bl[2][2], bh[2][2];

        // ===== phase 1: read afA(A-lo) + bl + bh; stage Ahi(kt+1);
        //       MFMA m0-3 x n0-1 (only lgkm-blocking cluster) =====
        #pragma unroll
        for (int m = 0; m < 4; ++m) {
            afA[m][0] = *(const bf16v8*)(aRd + bo + m * 2048 + kx0);
            afA[m][1] = *(const bf16v8*)(aRd + bo + m * 2048 + kx1);
        }
        #pragma unroll
        for (int n = 0; n < 2; ++n) {
            bl[n][0] = *(const bf16v8*)(bRd + bo + n * 2048 + kx0);
            bl[n][1] = *(const bf16v8*)(bRd + bo + n * 2048 + kx1);
            bh[n][0] = *(const bf16v8*)(bRd + bo + (n + 2) * 2048 + kx0);
            bh[n][1] = *(const bf16v8*)(bRd + bo + (n + 2) * 2048 + kx1);
        }
        STAGE_A(bn, 1, kk1);
        __builtin_amdgcn_s_setprio(1);
        #pragma unroll
        for (int m = 0; m < 4; ++m)
            #pragma unroll
            for (int n = 0; n < 2; ++n) {
                acc[m][n] = MFMA(afA[m][0], bl[n][0], acc[m][n], 0, 0, 0);
                acc[m][n] = MFMA(afA[m][1], bl[n][1], acc[m][n], 0, 0, 0);
            }
        __builtin_amdgcn_s_setprio(0);
        FENCE(); __builtin_amdgcn_s_barrier(); FENCE();

        // ===== phase 2: MFMA m0-3 x n2-3 (pre-read afA,bh); read afB(A-hi);
        //       stage Blo(kt+2) =====
        __builtin_amdgcn_s_setprio(1);
        #pragma unroll
        for (int m = 0; m < 4; ++m)
            #pragma unroll
            for (int n = 0; n < 2; ++n) {
                acc[m][n + 2] = MFMA(afA[m][0], bh[n][0], acc[m][n + 2], 0, 0, 0);
                acc[m][n + 2] = MFMA(afA[m][1], bh[n][1], acc[m][n + 2], 0, 0, 0);
            }
        __builtin_amdgcn_s_setprio(0);
        #pragma unroll
        for (int m = 0; m < 4; ++m) {
            afB[m][0] = *(const bf16v8*)(aRd + bo + (m + 4) * 2048 + kx0);
            afB[m][1] = *(const bf16v8*)(aRd + bo + (m + 4) * 2048 + kx1);
        }
        STAGE_B(bo, 0, kk2);
        FENCE(); __builtin_amdgcn_s_barrier(); FENCE();

        // ===== phase 3: MFMA m4-7 x n2-3 (pre-read afB,bh); stage Bhi(kt+2) =====
        __builtin_amdgcn_s_setprio(1);
        #pragma unroll
        for (int m = 0; m < 4; ++m)
            #pragma unroll
            for (int n = 0; n < 2; ++n) {
                acc[m + 4][n + 2] = MFMA(afB[m][0], bh[n][0], acc[m + 4][n + 2], 0, 0, 0);
                acc[m + 4][n + 2] = MFMA(afB[m][1], bh[n][1], acc[m + 4][n + 2], 0, 0, 0);
            }
        __builtin_amdgcn_s_setprio(0);
        STAGE_B(bo, 1, kk2);
        FENCE(); __builtin_amdgcn_s_barrier(); FENCE();

        // ===== phase 4: MFMA m4-7 x n0-1 (pre-read afB,bl); stage Alo(kt+2);
        //       vmcnt(6) =====
        __builtin_amdgcn_s_setprio(1);
        #pragma unroll
        for (int m = 0; m < 4; ++m)
            #pragma unroll
            for (int n = 0; n < 2; ++n) {
                acc[m + 4][n] = MFMA(afB[m][0], bl[n][0], acc[m + 4][n], 0, 0, 0);
                acc[m + 4][n] = MFMA(afB[m][1], bl[n][1], acc[m + 4][n], 0, 0, 0);
            }
        __builtin_amdgcn_s_setprio(0);
        STAGE_A(bo, 0, kk2);
        asm volatile("s_waitcnt vmcnt(6)" ::: "memory");
        FENCE(); __builtin_amdgcn_s_barrier(); FENCE();
    }

    // ---- fused norm + LoRA extension ----
    asm volatile("s_waitcnt vmcnt(0)" ::: "memory");
    __syncthreads();
    {
        bf16v8 zv;
        #pragma unroll
        for (int i = 0; i < 8; ++i) zv[i] = (__bf16)0.f;

        __bf16* tE  = (__bf16*)smem;           // [256][40] bf16 (pad 8)
        __bf16* LE  = (__bf16*)(smem + 20480); // [256][40]
        float*  gsf = (float*)(smem + 40960);  // G[16][16]
        const int bb = row0 >> 11;

        if (tid < 256) {
            float g = 0.f;
            #pragma unroll
            for (int c = 0; c < 8; ++c) g += gpart[((size_t)bb * 8 + c) * 256 + tid];
            gsf[tid] = g;
        }
        {
            const int r = tid >> 1;
            const int h = (tid & 1) * 8;
            const float* lp = lleft + ((size_t)bb * 16 + h) * 2048 + col0 + r;
            bf16v8 lv;
            #pragma unroll
            for (int i = 0; i < 8; ++i) lv[i] = (__bf16)lp[(size_t)i * 2048];
            *(bf16v8*)(LE + r * 40 + h) = lv;
            *(bf16v8*)(LE + r * 40 + 16 + h) = zv;
        }
        __syncthreads();
        if (tid < 256) {
            const float* tp = traw + (size_t)(row0 + tid) * 16;
            float4 a0 = *(const float4*)(tp);
            float4 a1 = *(const float4*)(tp + 4);
            float4 a2 = *(const float4*)(tp + 8);
            float4 a3 = *(const float4*)(tp + 12);
            float tv[16] = {a0.x, a0.y, a0.z, a0.w, a1.x, a1.y, a1.z, a1.w,
                            a2.x, a2.y, a2.z, a2.w, a3.x, a3.y, a3.z, a3.w};
            float q = 0.f;
            #pragma unroll
            for (int k = 0; k < 16; ++k) {
                float s = 0.f;
                #pragma unroll
                for (int j = 0; j < 16; ++j) s += gsf[k * 16 + j] * tv[j];
                q += tv[k] * s;
            }
            const float sc = SCALE_V * rsqrtf(q);
            bf16v8 t0v, t1v;
            #pragma unroll
            for (int i = 0; i < 8; ++i) {
                t0v[i] = (__bf16)(tv[i] * sc);
                t1v[i] = (__bf16)(tv[8 + i] * sc);
            }
            *(bf16v8*)(tE + tid * 40)      = t0v;
            *(bf16v8*)(tE + tid * 40 + 8)  = t1v;
            *(bf16v8*)(tE + tid * 40 + 16) = zv;
            *(bf16v8*)(tE + tid * 40 + 24) = zv;
        }
        __syncthreads();
    }
    {
        const __bf16* tE = (const __bf16*)smem;
        const __bf16* LE = (const __bf16*)(smem + 20480);
        const int ko = (lane >> 4) * 8;
        bf16v8 bE[4];
        #pragma unroll
        for (int n = 0; n < 4; ++n)
            bE[n] = *(const bf16v8*)(LE + (wn * 64 + n * 16 + fr) * 40 + ko);
        #pragma unroll
        for (int m = 0; m < 8; ++m) {
            bf16v8 aE = *(const bf16v8*)(tE + (wm * 128 + m * 16 + fr) * 40 + ko);
            #pragma unroll
            for (int n = 0; n < 4; ++n)
                acc[m][n] = MFMA(aE, bE[n], acc[m][n], 0, 0, 0);
        }
    }

    // ---- writeout + bias ----
    #pragma unroll
    for (int n = 0; n < 4; ++n) {
        const int gc = col0 + wn * 64 + n * 16 + fr;
        const float bv = bias[gc];
        #pragma unroll
        for (int m = 0; m < 8; ++m) {
            #pragma unroll
            for (int j = 0; j < 4; ++j) {
                const int gr = row0 + wm * 128 + m * 16 + (lane >> 4) * 4 + j;
                out[(size_t)gr * 2048 + gc] = acc[m][n][j] + bv;
            }
        }
    }
#undef STAGE_A
#undef STAGE_B
}

// ---------------------------------------------------------------------------
extern "C" void kernel_launch(void* const* d_in, const int* in_sizes, int n_in,
                              void* d_out, int out_size, void* d_ws, size_t ws_size,
                              hipStream_t stream) {
    const float* inp  = (const float*)d_in[0];   // [4,2048,2048]
    const float* wgt  = (const float*)d_in[1];   // [2048,2048]
    const float* bias = (const float*)d_in[2];   // [2048]
    const float* lrt  = (const float*)d_in[3];   // [4,2048,16]
    const float* llf  = (const float*)d_in[4];   // [4,16,2048]
    float* out = (float*)d_out;                  // [4,2048,2048]

    char* ws = (char*)d_ws;
    __bf16* abf  = (__bf16*)ws;                    // 33,554,432 B
    __bf16* wbf  = (__bf16*)(ws + 33554432);       //  8,388,608 B
    float*  tbuf = (float*)(ws + 41943040);        //    524,288 B (raw t)
    float*  gprt = (float*)(ws + 42467328);        //     32,768 B
    __bf16* lrT  = (__bf16*)(ws + 42500096);       //    262,144 B (bf16)

    transpose_lr_kernel<<<dim3(8, 4), 256, 0, stream>>>(lrt, lrT);
    prep_kernel<<<4128, 256, 0, stream>>>(inp, wgt, lrT, llf, abf, wbf, tbuf, gprt);
    gemm_ep_kernel<<<dim3(256), 512, 0, stream>>>(abf, wbf, bias, tbuf, gprt, llf, out);
}